// Round 4
// baseline (2427.387 us; speedup 1.0000x reference)
//
#include <hip/hip_runtime.h>
#include <hip/hip_bf16.h>

#define Bdim 64
#define Gdim 1024
#define Ddim 256
#define Fdim 1024

typedef short s8v __attribute__((ext_vector_type(8)));
typedef float f4v __attribute__((ext_vector_type(4)));

__device__ __forceinline__ float bf2f(short s){
  return __uint_as_float(((unsigned)(unsigned short)s) << 16);
}
__device__ __forceinline__ short f2bf(float f){
  unsigned u = __float_as_uint(f);
  u = u + 0x7fffu + ((u >> 16) & 1u);   // RNE
  return (short)(u >> 16);
}
__device__ __forceinline__ s8v ld8(const short* p){ return *(const s8v*)p; }

#define MFMA_BF16(a,b,c) __builtin_amdgcn_mfma_f32_16x16x32_bf16((a),(b),(c),0,0,0)

// ------------------------------------------------------------ dtype detection
__global__ __launch_bounds__(256) void detect_dtype(const unsigned* __restrict__ x,
                                                    int* __restrict__ flag){
  __shared__ int cnt[256];
  int c = 0;
  #pragma unroll
  for (int j=0;j<4;j++){
    unsigned u = x[threadIdx.x*4 + j];
    int e = (u >> 7) & 0xFF;
    c += (e >= 100 && e <= 140) ? 1 : 0;
  }
  cnt[threadIdx.x] = c;
  __syncthreads();
  if (threadIdx.x == 0){
    int s = 0;
    for (int i=0;i<256;i++) s += cnt[i];
    flag[0] = (s >= 512) ? 0 : 1;   // 0 = bf16 inputs, 1 = fp32 inputs
  }
}

// ------------------------------------------------------------ diagnostic
__global__ void diag_ws(void* o, float v, const int* __restrict__ flag){
  if (threadIdx.x == 0){
    if (flag[0]){ ((float*)o)[0] = v; ((float*)o)[16777216] = v; }
    else        { ((short*)o)[0] = f2bf(v); ((short*)o)[16777216] = f2bf(v); }
  }
}

// ------------------------------------------------------------ input -> fp32 h
__global__ __launch_bounds__(256) void cast_in(const void* __restrict__ x,
                                               float* __restrict__ h32,
                                               const int* __restrict__ flag){
  size_t i = ((size_t)blockIdx.x * 256 + threadIdx.x) * 8;
  if (flag[0]){
    const float* xf = (const float*)x;
    #pragma unroll
    for (int j=0;j<8;j++) h32[i+j] = xf[i+j];
  } else {
    s8v v = ld8((const short*)x + i);
    #pragma unroll
    for (int j=0;j<8;j++) h32[i+j] = bf2f(v[j]);
  }
}

// ------------------------------------------------------------ weight transpose -> bf16 hi (+lo)
template<int LO>
__global__ __launch_bounds__(256) void transpose2(const void* __restrict__ src,
                                                  short* __restrict__ dh,
                                                  short* __restrict__ dl, int R, int C,
                                                  const int* __restrict__ flag){
  __shared__ short th[32][33];
  __shared__ short tl[LO?32:1][33];
  int fl = flag[0];
  size_t off = (size_t)blockIdx.z * R * C;
  int c0 = blockIdx.x*32, r0 = blockIdx.y*32;
  int tx = threadIdx.x, ty = threadIdx.y;
  #pragma unroll
  for (int i=ty;i<32;i+=8){
    size_t idx = off + (size_t)(r0+i)*C + (c0+tx);
    float w = fl ? ((const float*)src)[idx] : bf2f(((const short*)src)[idx]);
    short hi = f2bf(w);
    th[i][tx] = hi;
    if (LO) tl[i][tx] = f2bf(w - bf2f(hi));
  }
  __syncthreads();
  #pragma unroll
  for (int i=ty;i<32;i+=8){
    size_t didx = off + (size_t)(c0+i)*R + (r0+tx);
    dh[didx] = th[tx][i];
    if (LO) dl[didx] = tl[tx][i];
  }
}

// ------------------------------------------------------------ biases -> fp32
// [0..511]=bo(2x256)  [512..2559]=bf1(2x1024)  [2560..3071]=bf2(2x256)
__global__ __launch_bounds__(256) void bias_prep(const void* __restrict__ bo,
                                                 const void* __restrict__ bf1,
                                                 const void* __restrict__ bf2,
                                                 float* __restrict__ biasf,
                                                 const int* __restrict__ flag){
  int fl = flag[0];
  int i = blockIdx.x*256 + threadIdx.x;
  const void* src; int idx;
  if (i < 512){ src = bo; idx = i; }
  else if (i < 2560){ src = bf1; idx = i - 512; }
  else { src = bf2; idx = i - 2560; }
  biasf[i] = fl ? ((const float*)src)[idx] : bf2f(((const short*)src)[idx]);
}

// ------------------------------------------------------------ GEMM template
// AM: 0 = A bf16 plane; 1 = A fp32 -> hi only; 2 = A fp32 -> hi+lo split
// BM: 0 = B bf16 hi only; 1 = B hi+lo split
// EPI: 0 = bf16 store; 1 = relu(acc+bias) bf16 store; 3 = bf16 transposed (V^T);
//      4 = h32[idx] += acc + bias (fp32 residual accumulate)
template<int AM, int BM, int EPI>
__global__ __launch_bounds__(256) void gemm_t(
    const void* __restrict__ Ap, const short* __restrict__ Bh,
    const short* __restrict__ Bl, const float* __restrict__ bias,
    float* __restrict__ hout, short* __restrict__ outb,
    int N, int K, int lda, int ldb)
{
  constexpr int AT = (AM==2) ? 2 : 1;
  constexpr int BT = (BM==1) ? 2 : 1;
  __shared__ short As[AT*128*40];
  __shared__ short Bs[BT*128*40];
  short* Asl = As + 128*40;
  short* Bsl = Bs + 128*40;
  const int tid = threadIdx.x;
  const int lane = tid & 63, wave = tid >> 6;
  const int quad = lane >> 4, l16 = lane & 15;
  const int m0 = blockIdx.x * 128, n0 = blockIdx.y * 128;
  const int wr = wave >> 1, wc = wave & 1;
  f4v acc[4][4];
  #pragma unroll
  for (int i=0;i<4;i++)
    #pragma unroll
    for (int j=0;j<4;j++) acc[i][j] = f4v{0.f,0.f,0.f,0.f};

  for (int k0 = 0; k0 < K; k0 += 32){
    __syncthreads();
    #pragma unroll
    for (int i=0;i<2;i++){
      int v = tid + i*256;
      int r = v >> 2, c8 = (v & 3) * 8;
      if (AM == 0){
        *(s8v*)(&As[r*40 + c8]) = ld8((const short*)Ap + (size_t)(m0 + r)*lda + k0 + c8);
      } else {
        const float* af = (const float*)Ap + (size_t)(m0 + r)*lda + k0 + c8;
        float4 f0 = *(const float4*)af;
        float4 f1 = *(const float4*)(af + 4);
        float fv[8] = {f0.x,f0.y,f0.z,f0.w,f1.x,f1.y,f1.z,f1.w};
        s8v hi, lo;
        #pragma unroll
        for (int j=0;j<8;j++) hi[j] = f2bf(fv[j]);
        *(s8v*)(&As[r*40 + c8]) = hi;
        if (AM == 2){
          #pragma unroll
          for (int j=0;j<8;j++) lo[j] = f2bf(fv[j] - bf2f(hi[j]));
          *(s8v*)(&Asl[r*40 + c8]) = lo;
        }
      }
      *(s8v*)(&Bs[r*40 + c8]) = ld8(Bh + (size_t)(n0 + r)*ldb + k0 + c8);
      if (BM == 1)
        *(s8v*)(&Bsl[r*40 + c8]) = ld8(Bl + (size_t)(n0 + r)*ldb + k0 + c8);
    }
    __syncthreads();
    s8v ah[4], al[4], bh[4], bl[4];
    #pragma unroll
    for (int t=0;t<4;t++){
      ah[t] = ld8(&As[(wr*64 + t*16 + l16)*40 + quad*8]);
      bh[t] = ld8(&Bs[(wc*64 + t*16 + l16)*40 + quad*8]);
      if (AM == 2) al[t] = ld8(&Asl[(wr*64 + t*16 + l16)*40 + quad*8]);
      if (BM == 1) bl[t] = ld8(&Bsl[(wc*64 + t*16 + l16)*40 + quad*8]);
    }
    #pragma unroll
    for (int ti=0;ti<4;ti++)
      #pragma unroll
      for (int tj=0;tj<4;tj++){
        acc[ti][tj] = MFMA_BF16(ah[ti], bh[tj], acc[ti][tj]);
        if (BM == 1) acc[ti][tj] = MFMA_BF16(ah[ti], bl[tj], acc[ti][tj]);
        if (AM == 2) acc[ti][tj] = MFMA_BF16(al[ti], bh[tj], acc[ti][tj]);
      }
  }
  #pragma unroll
  for (int tj=0;tj<4;tj++){
    int col = n0 + wc*64 + tj*16 + l16;
    float bs = bias ? bias[col] : 0.f;
    #pragma unroll
    for (int ti=0;ti<4;ti++){
      #pragma unroll
      for (int r=0;r<4;r++){
        int row = m0 + wr*64 + ti*16 + quad*4 + r;
        float v = acc[ti][tj][r];
        if (EPI == 0){
          outb[(size_t)row * N + col] = f2bf(v);
        } else if (EPI == 1){
          v += bs; v = v > 0.f ? v : 0.f;
          outb[(size_t)row * N + col] = f2bf(v);
        } else if (EPI == 3){
          int bb = row >> 10, g = row & 1023;
          outb[(size_t)bb * (Ddim*Gdim) + (size_t)col * Gdim + g] = f2bf(v);
        } else {
          size_t idx = (size_t)row * N + col;
          hout[idx] += v + bs;
        }
      }
    }
  }
}

// ------------------------------------------------------------ flash attention (chunk of 16 batches)
// grid (16 qtiles, 16 batches). Q,K bf16 [16384x256]; Vt bf16 [16][256][1024];
// H fp32 [16384x256]. mask pre-offset to chunk.
__global__ __launch_bounds__(256) void flash_attn(
    const short* __restrict__ Q, const short* __restrict__ Kmat,
    const short* __restrict__ Vt, const int* __restrict__ mask,
    float* __restrict__ H)
{
  __shared__ short Ks[64*264];
  __shared__ short Vs[128*80];
  __shared__ short Ps[4*16*80];
  const int tid = threadIdx.x;
  const int lane = tid & 63, wave = tid >> 6;
  const int quad = lane >> 4, l16 = lane & 15;
  const int b = blockIdx.y, qt = blockIdx.x;
  const short* Qb  = Q    + (size_t)b*Gdim*Ddim;
  const short* Kb  = Kmat + (size_t)b*Gdim*Ddim;
  const short* Vtb = Vt   + (size_t)b*Ddim*Gdim;
  const int qrow = qt*64 + wave*16 + l16;
  s8v qf[8];
  #pragma unroll
  for (int s=0;s<8;s++) qf[s] = ld8(Qb + (size_t)qrow*Ddim + s*32 + quad*8);
  float mrow[4], lrow[4];
  #pragma unroll
  for (int r=0;r<4;r++){ mrow[r] = -1e9f; lrow[r] = 0.f; }
  f4v O[16];
  #pragma unroll
  for (int t=0;t<16;t++) O[t] = f4v{0.f,0.f,0.f,0.f};
  short* Pw = Ps + wave*16*80;

  for (int kt=0; kt<16; kt++){
    const int k0 = kt*64;
    __syncthreads();
    #pragma unroll
    for (int i=0;i<8;i++){
      int v = tid + i*256;
      int r = v >> 5, c8 = (v & 31)*8;
      *(s8v*)(&Ks[r*264 + c8]) = ld8(Kb + (size_t)(k0 + r)*Ddim + c8);
    }
    __syncthreads();
    f4v sc[4];
    #pragma unroll
    for (int tj=0;tj<4;tj++) sc[tj] = f4v{0.f,0.f,0.f,0.f};
    #pragma unroll
    for (int st=0;st<8;st++){
      #pragma unroll
      for (int tj=0;tj<4;tj++){
        s8v kb = ld8(&Ks[(tj*16 + l16)*264 + st*32 + quad*8]);
        sc[tj] = MFMA_BF16(qf[st], kb, sc[tj]);
      }
    }
    int mk[4];
    #pragma unroll
    for (int tj=0;tj<4;tj++) mk[tj] = mask[b*Gdim + k0 + tj*16 + l16];
    float pvv[4][4];
    #pragma unroll
    for (int r=0;r<4;r++){
      float mx = -1e9f;
      #pragma unroll
      for (int tj=0;tj<4;tj++){
        float v = sc[tj][r] * 0.0625f;
        if (mk[tj]) v = -30.f;
        sc[tj][r] = v;
        mx = fmaxf(mx, v);
      }
      #pragma unroll
      for (int mm=1; mm<16; mm<<=1) mx = fmaxf(mx, __shfl_xor(mx, mm));
      float mn = fmaxf(mrow[r], mx);
      float al = __expf(mrow[r] - mn);
      mrow[r] = mn;
      float ps = 0.f;
      #pragma unroll
      for (int tj=0;tj<4;tj++){
        float e = __expf(sc[tj][r] - mn);
        ps += e;                         // masked entries stay in denominator (ref semantics)
        pvv[tj][r] = mk[tj] ? 0.f : e;   // zeroed in numerator
      }
      #pragma unroll
      for (int mm=1; mm<16; mm<<=1) ps += __shfl_xor(ps, mm);
      lrow[r] = lrow[r]*al + ps;
      #pragma unroll
      for (int t=0;t<16;t++) O[t][r] *= al;
    }
    #pragma unroll
    for (int tj=0;tj<4;tj++)
      #pragma unroll
      for (int r=0;r<4;r++)
        Pw[(quad*4 + r)*80 + tj*16 + l16] = f2bf(pvv[tj][r]);
    #pragma unroll
    for (int half=0; half<2; half++){
      __syncthreads();
      #pragma unroll
      for (int i=0;i<4;i++){
        int v = tid + i*256;
        int rr = v >> 3, c8 = (v & 7)*8;
        *(s8v*)(&Vs[rr*80 + c8]) = ld8(Vtb + (size_t)(half*128 + rr)*Gdim + k0 + c8);
      }
      __syncthreads();
      #pragma unroll
      for (int st=0; st<2; st++){
        s8v pa = ld8(&Pw[l16*80 + st*32 + quad*8]);
        #pragma unroll
        for (int tt=0; tt<8; tt++){
          s8v vb = ld8(&Vs[(tt*16 + l16)*80 + st*32 + quad*8]);
          O[half*8 + tt] = MFMA_BF16(pa, vb, O[half*8 + tt]);
        }
      }
    }
  }
  const size_t hb = 0;
  #pragma unroll
  for (int t=0;t<16;t++){
    #pragma unroll
    for (int r=0;r<4;r++){
      int row = qt*64 + wave*16 + quad*4 + r;
      int col = t*16 + l16;
      float dn = fmaxf(lrow[r], 1e-30f);
      H[((size_t)b*Gdim + row)*Ddim + col] = O[t][r] / dn;
    }
  }
  (void)hb;
}

// ------------------------------------------------------------ mean + output
__global__ __launch_bounds__(256) void mean_partial(const float* __restrict__ h32,
                                                    float* __restrict__ part){
  int b = blockIdx.x, c = blockIdx.y, d = threadIdx.x;
  float s = 0.f;
  for (int g = c*64; g < c*64 + 64; g++)
    s += h32[((size_t)b*Gdim + g)*Ddim + d];
  part[(b*16 + c)*Ddim + d] = s;
}
__global__ __launch_bounds__(256) void mean_final_dyn(const float* __restrict__ part,
                                                      void* __restrict__ out,
                                                      const int* __restrict__ flag){
  int i = blockIdx.x*256 + threadIdx.x;
  int b = i >> 8, d = i & 255;
  float s = 0.f;
  #pragma unroll
  for (int c=0;c<16;c++) s += part[(b*16 + c)*Ddim + d];
  s *= (1.f/1024.f);
  if (flag[0]) ((float*)out)[16777216 + i] = s;
  else         ((short*)out)[16777216 + i] = f2bf(s);
}
__global__ __launch_bounds__(256) void store_h(const float* __restrict__ h32,
                                               void* __restrict__ out,
                                               const int* __restrict__ flag){
  size_t i = (size_t)blockIdx.x*256 + threadIdx.x;
  if (flag[0]) ((float*)out)[i] = h32[i];
  else         ((short*)out)[i] = f2bf(h32[i]);
}

// ------------------------------------------------------------ launch
extern "C" void kernel_launch(void* const* d_in, const int* in_sizes, int n_in,
                              void* d_out, int out_size, void* d_ws, size_t ws_size,
                              hipStream_t stream)
{
  const void* xs  = d_in[0];
  const int*  mask= (const int*)d_in[1];
  const void* Wq  = d_in[2];
  const void* Wk  = d_in[3];
  const void* Wv  = d_in[4];
  const void* Wo  = d_in[5];
  const void* bo  = d_in[6];
  const void* Wf1 = d_in[7];
  const void* bf1 = d_in[8];
  const void* Wf2 = d_in[9];
  const void* bf2 = d_in[10];

  char* p = (char*)d_ws;
  int* flag = (int*)p; p += 256;
  float* h32 = (float*)p; p += 67108864;        // 64 MB fp32 h master
  char*  arena = p; p += 41943040;              // 40 MB chunk arena
  short* WqT  = (short*)p; p += 262144;
  short* WkT  = (short*)p; p += 262144;
  short* WvT  = (short*)p; p += 262144;
  short* WoTh = (short*)p; p += 262144;
  short* WoTl = (short*)p; p += 262144;
  short* Wf1h = (short*)p; p += 1048576;
  short* Wf1l = (short*)p; p += 1048576;
  short* Wf2h = (short*)p; p += 1048576;
  short* Wf2l = (short*)p; p += 1048576;
  float* biasf= (float*)p; p += 12288;
  float* part = (float*)p; p += 1048576;
  const size_t NEED = (size_t)(p - (char*)d_ws);

  detect_dtype<<<1, 256, 0, stream>>>((const unsigned*)xs, flag);
  if (ws_size < NEED){
    diag_ws<<<1, 64, 0, stream>>>(d_out, 2000.f + (float)(ws_size >> 20), flag);
    return;
  }
  // chunk arena layout (16 batches per chunk)
  short* Qc   = (short*)arena;                   // 8 MB
  short* Kc   = (short*)(arena + 8388608);       // 8 MB
  short* Vtc  = (short*)(arena + 16777216);      // 8 MB
  float* Hc   = (float*)(arena + 25165824);      // 16 MB (24..40)
  short* Tc   = (short*)arena;                   // 32 MB (reuses Q/K/Vt/H after O-proj)

  cast_in<<<8192, 256, 0, stream>>>(xs, h32, flag);
  dim3 tb(32,8);
  transpose2<0><<<dim3(8,8,2),  tb, 0, stream>>>(Wq,  WqT, nullptr, 256, 256, flag);
  transpose2<0><<<dim3(8,8,2),  tb, 0, stream>>>(Wk,  WkT, nullptr, 256, 256, flag);
  transpose2<0><<<dim3(8,8,2),  tb, 0, stream>>>(Wv,  WvT, nullptr, 256, 256, flag);
  transpose2<1><<<dim3(8,8,2),  tb, 0, stream>>>(Wo,  WoTh, WoTl, 256, 256, flag);
  transpose2<1><<<dim3(32,8,2), tb, 0, stream>>>(Wf1, Wf1h, Wf1l, 256, 1024, flag);
  transpose2<1><<<dim3(8,32,2), tb, 0, stream>>>(Wf2, Wf2h, Wf2l, 1024, 256, flag);
  bias_prep<<<12, 256, 0, stream>>>(bo, bf1, bf2, biasf, flag);

  for (int c=0; c<4; c++){
    float* hc = h32 + (size_t)c*16384*256;
    const int* mc = mask + c*16384;
    for (int l=0; l<2; l++){
      // QKV (A = fp32 h, hi-only; B = bf16 weights)
      gemm_t<1,0,0><<<dim3(128,2), 256, 0, stream>>>(hc, WqT + l*65536, nullptr, nullptr,
                                                     nullptr, Qc, 256, 256, 256, 256);
      gemm_t<1,0,0><<<dim3(128,2), 256, 0, stream>>>(hc, WkT + l*65536, nullptr, nullptr,
                                                     nullptr, Kc, 256, 256, 256, 256);
      gemm_t<1,0,3><<<dim3(128,2), 256, 0, stream>>>(hc, WvT + l*65536, nullptr, nullptr,
                                                     nullptr, Vtc, 256, 256, 256, 256);
      flash_attn<<<dim3(16,16), 256, 0, stream>>>(Qc, Kc, Vtc, mc, Hc);
      // O-proj: A = H fp32 split, B = Wo split, h32 += acc + bo
      gemm_t<2,1,4><<<dim3(128,2), 256, 0, stream>>>(Hc, WoTh + l*65536, WoTl + l*65536,
                                                     biasf + l*256, hc, nullptr, 256, 256, 256, 256);
      // FFN1: A = h fp32 split, B = Wf1 split, relu+bias -> T bf16
      gemm_t<2,1,1><<<dim3(128,8), 256, 0, stream>>>(hc, Wf1h + l*262144, Wf1l + l*262144,
                                                     biasf + 512 + l*1024, nullptr, Tc, 1024, 256, 256, 256);
      // FFN2: A = T bf16, B = Wf2 split, h32 += acc + bf2
      gemm_t<0,1,4><<<dim3(128,2), 256, 0, stream>>>(Tc, Wf2h + l*262144, Wf2l + l*262144,
                                                     biasf + 2560 + l*256, hc, nullptr, 256, 1024, 1024, 1024);
    }
  }
  mean_partial<<<dim3(64,16), 256, 0, stream>>>(h32, part);
  store_h<<<65536, 256, 0, stream>>>(h32, d_out, flag);
  mean_final_dyn<<<64, 256, 0, stream>>>(part, d_out, flag);
}

// Round 5
// 1445.500 us; speedup vs baseline: 1.6793x; 1.6793x over previous
//
#include <hip/hip_runtime.h>
#include <hip/hip_bf16.h>

#define Bdim 64
#define Gdim 1024
#define Ddim 256
#define Fdim 1024

typedef short s8v __attribute__((ext_vector_type(8)));
typedef float f4v __attribute__((ext_vector_type(4)));

__device__ __forceinline__ float bf2f(short s){
  return __uint_as_float(((unsigned)(unsigned short)s) << 16);
}
__device__ __forceinline__ short f2bf(float f){
  unsigned u = __float_as_uint(f);
  u = u + 0x7fffu + ((u >> 16) & 1u);   // RNE
  return (short)(u >> 16);
}
__device__ __forceinline__ s8v ld8(const short* p){ return *(const s8v*)p; }

#define MFMA_BF16(a,b,c) __builtin_amdgcn_mfma_f32_16x16x32_bf16((a),(b),(c),0,0,0)

// ------------------------------------------------------------ dtype detection
__global__ __launch_bounds__(256) void detect_dtype(const unsigned* __restrict__ x,
                                                    int* __restrict__ flag){
  __shared__ int cnt[256];
  int c = 0;
  #pragma unroll
  for (int j=0;j<4;j++){
    unsigned u = x[threadIdx.x*4 + j];
    int e = (u >> 7) & 0xFF;
    c += (e >= 100 && e <= 140) ? 1 : 0;
  }
  cnt[threadIdx.x] = c;
  __syncthreads();
  if (threadIdx.x == 0){
    int s = 0;
    for (int i=0;i<256;i++) s += cnt[i];
    flag[0] = (s >= 512) ? 0 : 1;   // 0 = bf16 inputs, 1 = fp32 inputs
  }
}

// ------------------------------------------------------------ diagnostic
__global__ void diag_ws(void* o, float v, const int* __restrict__ flag){
  if (threadIdx.x == 0){
    if (flag[0]){ ((float*)o)[0] = v; ((float*)o)[16777216] = v; }
    else        { ((short*)o)[0] = f2bf(v); ((short*)o)[16777216] = f2bf(v); }
  }
}

// ------------------------------------------------------------ input -> fp32 h
__global__ __launch_bounds__(256) void cast_in(const void* __restrict__ x,
                                               float* __restrict__ h32,
                                               const int* __restrict__ flag){
  size_t i = ((size_t)blockIdx.x * 256 + threadIdx.x) * 8;
  if (flag[0]){
    const float* xf = (const float*)x;
    #pragma unroll
    for (int j=0;j<8;j++) h32[i+j] = xf[i+j];
  } else {
    s8v v = ld8((const short*)x + i);
    #pragma unroll
    for (int j=0;j<8;j++) h32[i+j] = bf2f(v[j]);
  }
}

// ------------------------------------------------------------ weight transpose -> bf16, stackable dst
__global__ __launch_bounds__(256) void transpose_w(const void* __restrict__ src,
                                                   short* __restrict__ dh, int R, int C,
                                                   const int* __restrict__ flag,
                                                   int dzs, int dbase){
  __shared__ short th[32][33];
  int fl = flag[0];
  size_t soff = (size_t)blockIdx.z * R * C;
  size_t doff = (size_t)dbase + (size_t)blockIdx.z * dzs;
  int c0 = blockIdx.x*32, r0 = blockIdx.y*32;
  int tx = threadIdx.x, ty = threadIdx.y;
  #pragma unroll
  for (int i=ty;i<32;i+=8){
    size_t idx = soff + (size_t)(r0+i)*C + (c0+tx);
    float w = fl ? ((const float*)src)[idx] : bf2f(((const short*)src)[idx]);
    th[i][tx] = f2bf(w);
  }
  __syncthreads();
  #pragma unroll
  for (int i=ty;i<32;i+=8)
    dh[doff + (size_t)(c0+i)*R + (r0+tx)] = th[tx][i];
}

// ------------------------------------------------------------ biases -> fp32
// [0..511]=bo(2x256)  [512..2559]=bf1(2x1024)  [2560..3071]=bf2(2x256)
__global__ __launch_bounds__(256) void bias_prep(const void* __restrict__ bo,
                                                 const void* __restrict__ bf1,
                                                 const void* __restrict__ bf2,
                                                 float* __restrict__ biasf,
                                                 const int* __restrict__ flag){
  int fl = flag[0];
  int i = blockIdx.x*256 + threadIdx.x;
  const void* src; int idx;
  if (i < 512){ src = bo; idx = i; }
  else if (i < 2560){ src = bf1; idx = i - 512; }
  else { src = bf2; idx = i - 2560; }
  biasf[i] = fl ? ((const float*)src)[idx] : bf2f(((const short*)src)[idx]);
}

// ------------------------------------------------------------ GEMM template
// AM: 0 = A bf16; 1 = A fp32 -> hi only; 2 = A fp32 -> hi+lo split (2 MFMA)
// EPI: 0 = bf16 store; 1 = relu(acc+bias) bf16 store;
//      4 = h32[idx] += acc + bias; 5 = fused QKV routing (Q,K row-major; V transposed)
template<int AM, int EPI>
__global__ __launch_bounds__(256) void gemm_t(
    const void* __restrict__ Ap, const short* __restrict__ Bh,
    const float* __restrict__ bias, float* __restrict__ hout,
    short* __restrict__ outb, int N, int K, int lda, int ldb, int Mrows)
{
  constexpr int AT = (AM==2) ? 2 : 1;
  __shared__ short As[AT*128*40];
  __shared__ short Bs[128*40];
  short* Asl = As + 128*40;
  const int tid = threadIdx.x;
  const int lane = tid & 63, wave = tid >> 6;
  const int quad = lane >> 4, l16 = lane & 15;
  const int m0 = blockIdx.x * 128, n0 = blockIdx.y * 128;
  const int wr = wave >> 1, wc = wave & 1;
  f4v acc[4][4];
  #pragma unroll
  for (int i=0;i<4;i++)
    #pragma unroll
    for (int j=0;j<4;j++) acc[i][j] = f4v{0.f,0.f,0.f,0.f};

  for (int k0 = 0; k0 < K; k0 += 32){
    __syncthreads();
    #pragma unroll
    for (int i=0;i<2;i++){
      int v = tid + i*256;
      int r = v >> 2, c8 = (v & 3) * 8;
      if (AM == 0){
        *(s8v*)(&As[r*40 + c8]) = ld8((const short*)Ap + (size_t)(m0 + r)*lda + k0 + c8);
      } else {
        const float* af = (const float*)Ap + (size_t)(m0 + r)*lda + k0 + c8;
        float4 f0 = *(const float4*)af;
        float4 f1 = *(const float4*)(af + 4);
        float fv[8] = {f0.x,f0.y,f0.z,f0.w,f1.x,f1.y,f1.z,f1.w};
        s8v hi, lo;
        #pragma unroll
        for (int j=0;j<8;j++) hi[j] = f2bf(fv[j]);
        *(s8v*)(&As[r*40 + c8]) = hi;
        if (AM == 2){
          #pragma unroll
          for (int j=0;j<8;j++) lo[j] = f2bf(fv[j] - bf2f(hi[j]));
          *(s8v*)(&Asl[r*40 + c8]) = lo;
        }
      }
      *(s8v*)(&Bs[r*40 + c8]) = ld8(Bh + (size_t)(n0 + r)*ldb + k0 + c8);
    }
    __syncthreads();
    s8v ah[4], al[4], bh[4];
    #pragma unroll
    for (int t=0;t<4;t++){
      ah[t] = ld8(&As[(wr*64 + t*16 + l16)*40 + quad*8]);
      bh[t] = ld8(&Bs[(wc*64 + t*16 + l16)*40 + quad*8]);
      if (AM == 2) al[t] = ld8(&Asl[(wr*64 + t*16 + l16)*40 + quad*8]);
    }
    #pragma unroll
    for (int ti=0;ti<4;ti++)
      #pragma unroll
      for (int tj=0;tj<4;tj++){
        acc[ti][tj] = MFMA_BF16(ah[ti], bh[tj], acc[ti][tj]);
        if (AM == 2) acc[ti][tj] = MFMA_BF16(al[ti], bh[tj], acc[ti][tj]);
      }
  }
  #pragma unroll
  for (int tj=0;tj<4;tj++){
    int col = n0 + wc*64 + tj*16 + l16;
    float bs = (EPI==1 || EPI==4) ? (bias ? bias[col] : 0.f) : 0.f;
    #pragma unroll
    for (int ti=0;ti<4;ti++){
      #pragma unroll
      for (int r=0;r<4;r++){
        int row = m0 + wr*64 + ti*16 + quad*4 + r;
        float v = acc[ti][tj][r];
        if (EPI == 0){
          outb[(size_t)row * N + col] = f2bf(v);
        } else if (EPI == 1){
          v += bs; v = v > 0.f ? v : 0.f;
          outb[(size_t)row * N + col] = f2bf(v);
        } else if (EPI == 4){
          size_t idx = (size_t)row * N + col;
          hout[idx] += v + bs;
        } else {  // EPI == 5: fused QKV
          int sec = col >> 8, c = col & 255;
          if (sec == 0)      outb[(size_t)row*256 + c] = f2bf(v);
          else if (sec == 1) (outb + (size_t)Mrows*256)[(size_t)row*256 + c] = f2bf(v);
          else {
            int bb = row >> 10, g = row & 1023;
            (outb + (size_t)2*Mrows*256)[(size_t)bb*262144 + (size_t)c*1024 + g] = f2bf(v);
          }
        }
      }
    }
  }
}

// ------------------------------------------------------------ flash attention
// grid (16 qtiles, CB batches). Q,K bf16 [CB*1024 x 256]; Vt bf16 [CB][256][1024];
// H bf16 [CB*1024 x 256]. Union LDS: K-tile [64][264] then V^T-tile [256][72].
__global__ __launch_bounds__(256) void flash_attn(
    const short* __restrict__ Q, const short* __restrict__ Kmat,
    const short* __restrict__ Vt, const int* __restrict__ mask,
    short* __restrict__ H)
{
  __shared__ short KV[18432];     // 36,864 B: K view 64*264=16,896; V view 256*72=18,432
  __shared__ short Ps[4*16*72];   //  9,216 B: per-wave P [16 qrows][64 keys], stride 72
  const int tid = threadIdx.x;
  const int lane = tid & 63, wave = tid >> 6;
  const int quad = lane >> 4, l16 = lane & 15;
  const int b = blockIdx.y, qt = blockIdx.x;
  const short* Qb  = Q    + (size_t)b*Gdim*Ddim;
  const short* Kb  = Kmat + (size_t)b*Gdim*Ddim;
  const short* Vtb = Vt   + (size_t)b*Ddim*Gdim;
  const int qrow = qt*64 + wave*16 + l16;
  s8v qf[8];
  #pragma unroll
  for (int s=0;s<8;s++) qf[s] = ld8(Qb + (size_t)qrow*Ddim + s*32 + quad*8);
  float mrow[4], lrow[4];
  #pragma unroll
  for (int r=0;r<4;r++){ mrow[r] = -1e9f; lrow[r] = 0.f; }
  f4v O[16];
  #pragma unroll
  for (int t=0;t<16;t++) O[t] = f4v{0.f,0.f,0.f,0.f};
  short* Pw = Ps + wave*16*72;

  for (int kt=0; kt<16; kt++){
    const int k0 = kt*64;
    __syncthreads();                      // prev PV done reading KV
    #pragma unroll
    for (int i=0;i<8;i++){                // stage K-tile [64][264]
      int v = tid + i*256;
      int r = v >> 5, c8 = (v & 31)*8;
      *(s8v*)(&KV[r*264 + c8]) = ld8(Kb + (size_t)(k0 + r)*Ddim + c8);
    }
    __syncthreads();
    f4v sc[4];
    #pragma unroll
    for (int tj=0;tj<4;tj++) sc[tj] = f4v{0.f,0.f,0.f,0.f};
    #pragma unroll
    for (int st=0;st<8;st++){
      #pragma unroll
      for (int tj=0;tj<4;tj++){
        s8v kb = ld8(&KV[(tj*16 + l16)*264 + st*32 + quad*8]);
        sc[tj] = MFMA_BF16(qf[st], kb, sc[tj]);
      }
    }
    int mk[4];
    #pragma unroll
    for (int tj=0;tj<4;tj++) mk[tj] = mask[b*Gdim + k0 + tj*16 + l16];
    float al[4], pvv[4][4];
    bool need = false;
    #pragma unroll
    for (int r=0;r<4;r++){
      float mx = -1e9f;
      #pragma unroll
      for (int tj=0;tj<4;tj++){
        float v = sc[tj][r] * 0.0625f;
        if (mk[tj]) v = -30.f;
        sc[tj][r] = v;
        mx = fmaxf(mx, v);
      }
      #pragma unroll
      for (int mm=1; mm<16; mm<<=1) mx = fmaxf(mx, __shfl_xor(mx, mm));
      float mn = fmaxf(mrow[r], mx);
      al[r] = __expf(mrow[r] - mn);
      need |= (al[r] < 1.f);
      mrow[r] = mn;
      float ps = 0.f;
      #pragma unroll
      for (int tj=0;tj<4;tj++){
        float e = __expf(sc[tj][r] - mn);
        ps += e;                         // masked entries stay in denominator (ref semantics)
        pvv[tj][r] = mk[tj] ? 0.f : e;   // zeroed in numerator
      }
      #pragma unroll
      for (int mm=1; mm<16; mm<<=1) ps += __shfl_xor(ps, mm);
      lrow[r] = lrow[r]*al[r] + ps;
    }
    if (__any(need)){
      #pragma unroll
      for (int t=0;t<16;t++)
        #pragma unroll
        for (int r=0;r<4;r++) O[t][r] *= al[r];
    }
    #pragma unroll
    for (int tj=0;tj<4;tj++)
      #pragma unroll
      for (int r=0;r<4;r++)
        Pw[(quad*4 + r)*72 + tj*16 + l16] = f2bf(pvv[tj][r]);
    __syncthreads();                      // all waves done reading K-tile
    #pragma unroll
    for (int i=0;i<8;i++){                // stage V^T-tile [256][72]
      int v = tid + i*256;
      int rr = v >> 3, c8 = (v & 7)*8;
      *(s8v*)(&KV[rr*72 + c8]) = ld8(Vtb + (size_t)rr*Gdim + k0 + c8);
    }
    __syncthreads();
    #pragma unroll
    for (int st=0; st<2; st++){
      s8v pa = ld8(&Pw[l16*72 + st*32 + quad*8]);
      #pragma unroll
      for (int tt=0; tt<16; tt++){
        s8v vb = ld8(&KV[(tt*16 + l16)*72 + st*32 + quad*8]);
        O[tt] = MFMA_BF16(pa, vb, O[tt]);
      }
    }
  }
  #pragma unroll
  for (int t=0;t<16;t++){
    #pragma unroll
    for (int r=0;r<4;r++){
      int row = qt*64 + wave*16 + quad*4 + r;
      int col = t*16 + l16;
      float dn = fmaxf(lrow[r], 1e-30f);
      H[((size_t)b*Gdim + row)*Ddim + col] = f2bf(O[t][r] / dn);
    }
  }
}

// ------------------------------------------------------------ mean + output
__global__ __launch_bounds__(256) void mean_partial(const float* __restrict__ h32,
                                                    float* __restrict__ part){
  int b = blockIdx.x, c = blockIdx.y, d = threadIdx.x;
  float s = 0.f;
  for (int g = c*64; g < c*64 + 64; g++)
    s += h32[((size_t)b*Gdim + g)*Ddim + d];
  part[(b*16 + c)*Ddim + d] = s;
}
__global__ __launch_bounds__(256) void mean_final_dyn(const float* __restrict__ part,
                                                      void* __restrict__ out,
                                                      const int* __restrict__ flag){
  int i = blockIdx.x*256 + threadIdx.x;
  int b = i >> 8, d = i & 255;
  float s = 0.f;
  #pragma unroll
  for (int c=0;c<16;c++) s += part[(b*16 + c)*Ddim + d];
  s *= (1.f/1024.f);
  if (flag[0]) ((float*)out)[16777216 + i] = s;
  else         ((short*)out)[16777216 + i] = f2bf(s);
}
__global__ __launch_bounds__(256) void store_h(const float* __restrict__ h32,
                                               void* __restrict__ out,
                                               const int* __restrict__ flag){
  size_t i = (size_t)blockIdx.x*256 + threadIdx.x;
  if (flag[0]) ((float*)out)[i] = h32[i];
  else         ((short*)out)[i] = f2bf(h32[i]);
}

// ------------------------------------------------------------ launch
extern "C" void kernel_launch(void* const* d_in, const int* in_sizes, int n_in,
                              void* d_out, int out_size, void* d_ws, size_t ws_size,
                              hipStream_t stream)
{
  const void* xs  = d_in[0];
  const int*  mask= (const int*)d_in[1];
  const void* Wq  = d_in[2];
  const void* Wk  = d_in[3];
  const void* Wv  = d_in[4];
  const void* Wo  = d_in[5];
  const void* bo  = d_in[6];
  const void* Wf1 = d_in[7];
  const void* bf1 = d_in[8];
  const void* Wf2 = d_in[9];
  const void* bf2 = d_in[10];

  // weights: Wqkv(768K) + Wo(256K) + Wf1(1M) + Wf2(1M) + biasf(12K)
  const size_t W_ALL = 786432 + 262144 + 1048576 + 1048576 + 12288;  // 3,158,016
  const size_t BASE  = 256 + 67108864;                               // flag + h32
  int CB;
  if      (ws_size >= BASE + 134217728ull + W_ALL) CB = 64;   // 204.5 MB
  else if (ws_size >= BASE +  67108864ull + W_ALL) CB = 32;   // 137.4 MB (proven reachable)
  else if (ws_size >= BASE +  33554432ull + W_ALL) CB = 16;
  else CB = 0;

  char* p = (char*)d_ws;
  int* flag = (int*)p; p += 256;
  detect_dtype<<<1, 256, 0, stream>>>((const unsigned*)xs, flag);
  if (CB == 0){
    diag_ws<<<1, 64, 0, stream>>>(d_out, 2000.f + (float)(ws_size >> 20), flag);
    return;
  }
  const int M = CB * 1024, nch = 64 / CB;
  float* h32 = (float*)p; p += 67108864;
  char* arena = p;        p += (size_t)CB * 2097152;
  short* WqkvT = (short*)p; p += 786432;
  short* WoT   = (short*)p; p += 262144;
  short* Wf1T  = (short*)p; p += 1048576;
  short* Wf2T  = (short*)p; p += 1048576;
  float* biasf = (float*)p; p += 12288;
  float* part  = (float*)arena;          // arena dead by mean time

  short* Qc  = (short*)arena;
  short* Kc  = Qc + (size_t)M*256;
  short* Vtc = Qc + (size_t)2*M*256;
  short* Hc  = Qc + (size_t)3*M*256;
  short* Tc  = Qc;                       // FFN intermediate spans whole arena

  cast_in<<<8192, 256, 0, stream>>>(xs, h32, flag);
  dim3 tb(32,8);
  transpose_w<<<dim3(8,8,2),  tb, 0, stream>>>(Wq,  WqkvT, 256, 256,  flag, 196608, 0);
  transpose_w<<<dim3(8,8,2),  tb, 0, stream>>>(Wk,  WqkvT, 256, 256,  flag, 196608, 65536);
  transpose_w<<<dim3(8,8,2),  tb, 0, stream>>>(Wv,  WqkvT, 256, 256,  flag, 196608, 131072);
  transpose_w<<<dim3(8,8,2),  tb, 0, stream>>>(Wo,  WoT,   256, 256,  flag, 65536, 0);
  transpose_w<<<dim3(32,8,2), tb, 0, stream>>>(Wf1, Wf1T,  256, 1024, flag, 262144, 0);
  transpose_w<<<dim3(8,32,2), tb, 0, stream>>>(Wf2, Wf2T,  1024, 256, flag, 262144, 0);
  bias_prep<<<12, 256, 0, stream>>>(bo, bf1, bf2, biasf, flag);

  for (int c=0; c<nch; c++){
    float* hc = h32 + (size_t)c*M*256;
    const int* mc = mask + (size_t)c*M;
    for (int l=0; l<2; l++){
      // fused QKV: A = h fp32 (hi), B = stacked [768][256]
      gemm_t<1,5><<<dim3(M/128,6), 256, 0, stream>>>(hc, WqkvT + l*196608, nullptr,
                                                     nullptr, Qc, 768, 256, 256, 256, M);
      flash_attn<<<dim3(16,CB), 256, 0, stream>>>(Qc, Kc, Vtc, mc, Hc);
      // O-proj: h32 += Hc*Wo + bo
      gemm_t<0,4><<<dim3(M/128,2), 256, 0, stream>>>(Hc, WoT + l*65536, biasf + l*256,
                                                     hc, nullptr, 256, 256, 256, 256, M);
      // FFN1: T = relu(h*Wf1 + b), A split
      gemm_t<2,1><<<dim3(M/128,8), 256, 0, stream>>>(hc, Wf1T + l*262144, biasf + 512 + l*1024,
                                                     nullptr, Tc, 1024, 256, 256, 256, M);
      // FFN2: h32 += T*Wf2 + b
      gemm_t<0,4><<<dim3(M/128,2), 256, 0, stream>>>(Tc, Wf2T + l*262144, biasf + 2560 + l*256,
                                                     hc, nullptr, 256, 1024, 1024, 1024, M);
    }
  }
  mean_partial<<<dim3(64,16), 256, 0, stream>>>(h32, part);
  store_h<<<65536, 256, 0, stream>>>(h32, d_out, flag);
  mean_final_dyn<<<64, 256, 0, stream>>>(part, d_out, flag);
}